// Round 1
// baseline (256.143 us; speedup 1.0000x reference)
//
#include <hip/hip_runtime.h>

// RoiAlign / crop_and_resize: B=8, H=64, W=64, C=256, N=512, POOL=7
// out[b,n,py,px,c] = bilinear(fm[b], y(b,n,py), x(b,n,px)) with TF
// crop_and_resize semantics (zero outside [0,size-1]).
//
// One 64-lane wave per output pixel; lane l handles channels [4l,4l+4) as
// float4. All global accesses are 16B/lane coalesced. Memory-bound:
// ~205MB write + ~33.5MB compulsory read; fm fits in L3.

#define POOL  7
#define B_    8
#define H_    64
#define W_    64
#define C_    256
#define N_    512

__global__ __launch_bounds__(256) void roialign_kernel(
    const float* __restrict__ fm,      // [B,H,W,C]
    const float* __restrict__ boxes,   // [B,N,4] = x1,y1,x2,y2 normalized
    float* __restrict__ out)           // [B,N,POOL,POOL,C]
{
    const int gid  = blockIdx.x * 256 + threadIdx.x;
    const int lane = gid & 63;        // channel group: 64 lanes x float4 = 256 ch
    const int pix  = gid >> 6;        // output pixel index
    if (pix >= B_ * N_ * POOL * POOL) return;

    const int px  = pix % POOL;
    int tmp       = pix / POOL;
    const int py  = tmp % POOL;
    tmp          /= POOL;
    const int n   = tmp & (N_ - 1);
    const int b   = tmp >> 9;         // N_=512

    const float* box = boxes + ((b << 9) + n) * 4;
    const float bx1 = box[0], by1 = box[1], bx2 = box[2], by2 = box[3];

    // Match reference expression order exactly:
    //   ys = y1*(H-1) + i * ((y2-y1)*(H-1)/(POOL-1))
    const float sy = (by2 - by1) * 63.0f / 6.0f;
    const float sx = (bx2 - bx1) * 63.0f / 6.0f;
    const float yv = by1 * 63.0f + (float)py * sy;
    const float xv = bx1 * 63.0f + (float)px * sx;

    const float yf = floorf(yv), xf = floorf(xv);
    const float fy = yv - yf,    fx = xv - xf;
    const int   y0 = (int)yf,    x0 = (int)xf;

    const int yt = min(max(y0,     0), H_ - 1);
    const int yb = min(max(y0 + 1, 0), H_ - 1);
    const int xl = min(max(x0,     0), W_ - 1);
    const int xr = min(max(x0 + 1, 0), W_ - 1);

    const bool valid = (yv >= 0.0f) && (yv <= (float)(H_ - 1)) &&
                       (xv >= 0.0f) && (xv <= (float)(W_ - 1));

    const int cw = C_ / 4;  // 64 float4 per spatial pixel
    const float4* f4 = (const float4*)fm;
    const int imgbase = b * (H_ * W_ * cw);

    const float4 tl = f4[imgbase + (yt * W_ + xl) * cw + lane];
    const float4 tr = f4[imgbase + (yt * W_ + xr) * cw + lane];
    const float4 bl = f4[imgbase + (yb * W_ + xl) * cw + lane];
    const float4 br = f4[imgbase + (yb * W_ + xr) * cw + lane];

    float4 o;
    {
        const float tx = tl.x + (tr.x - tl.x) * fx;
        const float bx = bl.x + (br.x - bl.x) * fx;
        o.x = tx + (bx - tx) * fy;
        const float ty = tl.y + (tr.y - tl.y) * fx;
        const float by = bl.y + (br.y - bl.y) * fx;
        o.y = ty + (by - ty) * fy;
        const float tz = tl.z + (tr.z - tl.z) * fx;
        const float bz = bl.z + (br.z - bl.z) * fx;
        o.z = tz + (bz - tz) * fy;
        const float tw = tl.w + (tr.w - tl.w) * fx;
        const float bw = bl.w + (br.w - bl.w) * fx;
        o.w = tw + (bw - tw) * fy;
    }
    if (!valid) { o.x = 0.0f; o.y = 0.0f; o.z = 0.0f; o.w = 0.0f; }

    ((float4*)out)[pix * cw + lane] = o;
}

extern "C" void kernel_launch(void* const* d_in, const int* in_sizes, int n_in,
                              void* d_out, int out_size, void* d_ws, size_t ws_size,
                              hipStream_t stream) {
    const float* fm    = (const float*)d_in[0];   // [8,64,64,256] fp32
    const float* boxes = (const float*)d_in[1];   // [8,512,4] fp32
    float* out         = (float*)d_out;           // [8,512,7,7,256] fp32

    const int total_pix = B_ * N_ * POOL * POOL;      // 200704
    const int threads   = total_pix * 64;             // one wave per pixel
    const int blocks    = (threads + 255) / 256;      // 50176

    roialign_kernel<<<blocks, 256, 0, stream>>>(fm, boxes, out);
}